// Round 18
// baseline (207.417 us; speedup 1.0000x reference)
//
#include <hip/hip_runtime.h>

using u16 = unsigned short;
using u32 = unsigned int;

typedef __bf16 bf16x8 __attribute__((ext_vector_type(8)));
typedef float  f32x4  __attribute__((ext_vector_type(4)));

__device__ __forceinline__ u16 f2bf(float f) {
    u32 u = __float_as_uint(f);
    u32 r = u + 0x7fffu + ((u >> 16) & 1u);
    return (u16)(r >> 16);
}
__device__ __forceinline__ float gelu_f(float x) {
    return 0.5f * x * (1.0f + erff(x * 0.70710678118654752440f));
}

#define GLOAD16(gp, lp) __builtin_amdgcn_global_load_lds( \
    (const __attribute__((address_space(1))) void*)(gp),  \
    (__attribute__((address_space(3))) void*)(lp), 16, 0, 0)
#define WAITV10 asm volatile("s_waitcnt vmcnt(10)" ::: "memory")
#define WAITV6  asm volatile("s_waitcnt vmcnt(6)" ::: "memory")
#define WAITV4  asm volatile("s_waitcnt vmcnt(4)" ::: "memory")
#define WAITV2  asm volatile("s_waitcnt vmcnt(2)" ::: "memory")
#define WAITV0  asm volatile("s_waitcnt vmcnt(0)" ::: "memory")
#define WAITL0  asm volatile("s_waitcnt lgkmcnt(0)" ::: "memory")

// ---------------- prep: cvt x/W1/W2 -> bf16, zero score buffers ----------------
__global__ __launch_bounds__(256) void prep_kernel(
    const float* __restrict__ x, const float* __restrict__ W1, const float* __restrict__ W2,
    u16* __restrict__ Xb, u16* __restrict__ W1b, u16* __restrict__ W2b,
    float* __restrict__ Z)
{
    const int i0 = blockIdx.x * 256 + threadIdx.x;
    const int stride = gridDim.x * 256;
    if (i0 < 32768) ((float4*)Z)[i0] = make_float4(0.f, 0.f, 0.f, 0.f);
    for (int i = i0; i < 65536; i += stride) {
        float4 v = ((const float4*)W1)[i];
        ushort4 o; o.x = f2bf(v.x); o.y = f2bf(v.y); o.z = f2bf(v.z); o.w = f2bf(v.w);
        ((ushort4*)W1b)[i] = o;
    }
    for (int i = i0; i < 65536; i += stride) {
        float4 v = ((const float4*)W2)[i];
        ushort4 o; o.x = f2bf(v.x); o.y = f2bf(v.y); o.z = f2bf(v.z); o.w = f2bf(v.w);
        ((ushort4*)W2b)[i] = o;
    }
    for (int i = i0; i < 4194304; i += stride) {
        float4 v = ((const float4*)x)[i];
        ushort4 o; o.x = f2bf(v.x); o.y = f2bf(v.y); o.z = f2bf(v.z); o.w = f2bf(v.w);
        ((ushort4*)Xb)[i] = o;
    }
}

// ---------------- kernel A: GEMM (A in LDS, B in regs) + H^T + fused scores ----------------
// Block = (graph g, f-tile tn): 4 waves, 128m x 128f, BK=32.
// A: pair-row XOR swizzled LDS (R15-verified, 0 conflicts), counted-vmcnt dbuf.
// B: per-lane register fragments from plain bf16 W (L2-resident), two alternating
//    sets wA/wB prefetched one kt ahead (compiler inserts the reg waits).
// Per-wave VMEM issue order/iter: A-GLOAD(kt+2) x2, B-prefetch(kt+2) x4.
// At top of kt: A(kt) is 10 ops old -> WAITV10 (B(kt)+A(kt+1)+B(kt+1) stay in flight).
// XCD remap: bid' = (bid&7)*128 + bid>>3.
__global__ __launch_bounds__(256) void gat_gemm(
    const u16* __restrict__ A, const u16* __restrict__ Wb,
    const float* __restrict__ a_s, const float* __restrict__ a_d,
    u16* __restrict__ HT, float* __restrict__ SS, float* __restrict__ SD)
{
    __shared__ __align__(16) u16 As[2][128 * 32];
    __shared__ float sA[128], dA[128];

    const int tid  = threadIdx.x;
    const int lane = tid & 63;
    const int w    = tid >> 6;       // wave 0..3
    const int wm   = w & 1, wn = w >> 1;
    const int fr   = lane & 15;
    const int grp  = lane >> 4;
    const int bid  = (blockIdx.x & 7) * 128 + (blockIdx.x >> 3);   // XCD-grouped
    const int g    = bid >> 2;
    const int tn   = (bid & 3) * 128;

    if (tid < 128) { sA[tid] = 0.f; dA[tid] = 0.f; }

    // A staging source (pre-swizzled pair-row): cs = l7^l3
    const int l3 = lane >> 3, l7 = lane & 7;
    const int cs = l7 ^ l3;
    const u16* Ag0 = A + (size_t)g * 65536
                   + (size_t)(w * 32 + 2 * l3 + (cs >> 2)) * 512 + (cs & 3) * 8;

    // B register source: lane's fragment f = tn + wn*64 + j*16 + fr, k = kt*32 + grp*8
    const u16* wg = Wb + (size_t)(tn + wn * 64 + fr) * 512 + grp * 8;

    // A fragment read offset (lane-constant, swizzle folded)
    const int sw = ((((fr & 1) << 2) | grp) ^ ((fr >> 1) & 7)) * 8;

    f32x4 acc[4][4] = {};

    // prologue: A tiles 0,1 via GLOAD16; B tiles 0,1 into regs
    GLOAD16(Ag0,                 &As[0][w * 1024]);
    GLOAD16(Ag0 + 16 * 512,      &As[0][w * 1024 + 512]);
    GLOAD16(Ag0 + 32,            &As[1][w * 1024]);
    GLOAD16(Ag0 + 16 * 512 + 32, &As[1][w * 1024 + 512]);
    bf16x8 wA[4], wB[4];
    #pragma unroll
    for (int j = 0; j < 4; ++j) wA[j] = *(const bf16x8*)&wg[j * 16 * 512];
    #pragma unroll
    for (int j = 0; j < 4; ++j) wB[j] = *(const bf16x8*)&wg[j * 16 * 512 + 32];

    #pragma unroll 2
    for (int kt = 0; kt < 16; ++kt) {
        const int cur = kt & 1;
        if (kt < 15) { WAITV10; } else { WAITV4; }  // this wave's A(kt) landed
        __builtin_amdgcn_s_barrier();               // all waves' A(kt) visible
        bf16x8 af[4];
        #pragma unroll
        for (int i = 0; i < 4; ++i)
            af[i] = *(const bf16x8*)&As[cur][(wm * 32 + i * 8 + (fr >> 1)) * 64 + sw];
        WAITL0;                                     // af in regs
        __builtin_amdgcn_sched_barrier(0);
        __builtin_amdgcn_s_barrier();               // all waves done reading As[cur]
        if (kt < 14) {                              // re-stage As[cur] with tile kt+2
            GLOAD16(Ag0 + (kt + 2) * 32,            &As[cur][w * 1024]);
            GLOAD16(Ag0 + 16 * 512 + (kt + 2) * 32, &As[cur][w * 1024 + 512]);
        }
        if (cur == 0) {
            #pragma unroll
            for (int i = 0; i < 4; ++i)
                #pragma unroll
                for (int j = 0; j < 4; ++j)
                    acc[i][j] = __builtin_amdgcn_mfma_f32_16x16x32_bf16(af[i], wA[j], acc[i][j], 0, 0, 0);
            if (kt < 14) {
                #pragma unroll
                for (int j = 0; j < 4; ++j)
                    wA[j] = *(const bf16x8*)&wg[j * 16 * 512 + (kt + 2) * 32];
            }
        } else {
            #pragma unroll
            for (int i = 0; i < 4; ++i)
                #pragma unroll
                for (int j = 0; j < 4; ++j)
                    acc[i][j] = __builtin_amdgcn_mfma_f32_16x16x32_bf16(af[i], wB[j], acc[i][j], 0, 0, 0);
            if (kt < 14) {
                #pragma unroll
                for (int j = 0; j < 4; ++j)
                    wB[j] = *(const bf16x8*)&wg[j * 16 * 512 + (kt + 2) * 32];
            }
        }
    }

    // ---- epilogue: H^T write + fused scores ----
    float asv[4], adv[4];
    #pragma unroll
    for (int j = 0; j < 4; ++j) {
        int f = tn + wn * 64 + j * 16 + fr;
        asv[j] = a_s[f]; adv[j] = a_d[f];
    }
    u16* Hg = HT + (size_t)g * 65536;
    #pragma unroll
    for (int i = 0; i < 4; ++i) {
        int node0 = wm * 64 + i * 16 + grp * 4;
        #pragma unroll
        for (int j = 0; j < 4; ++j) {
            int f = tn + wn * 64 + j * 16 + fr;
            ushort4 o;
            o.x = f2bf(acc[i][j][0]); o.y = f2bf(acc[i][j][1]);
            o.z = f2bf(acc[i][j][2]); o.w = f2bf(acc[i][j][3]);
            *(ushort4*)&Hg[(size_t)f * 128 + node0] = o;
        }
        #pragma unroll
        for (int r = 0; r < 4; ++r) {
            float s = acc[i][0][r] * asv[0] + acc[i][1][r] * asv[1]
                    + acc[i][2][r] * asv[2] + acc[i][3][r] * asv[3];
            float d = acc[i][0][r] * adv[0] + acc[i][1][r] * adv[1]
                    + acc[i][2][r] * adv[2] + acc[i][3][r] * adv[3];
            #pragma unroll
            for (int off = 1; off < 16; off <<= 1) {
                s += __shfl_xor(s, off);
                d += __shfl_xor(d, off);
            }
            if (fr == 0) {
                atomicAdd(&sA[node0 + r], s);
                atomicAdd(&dA[node0 + r], d);
            }
        }
    }
    __syncthreads();
    if (tid < 128) {
        atomicAdd(&SS[g * 128 + tid], sA[tid]);
        atomicAdd(&SD[g * 128 + tid], dA[tid]);
    }
}

// ---------------- kernel B: alpha + AGG, 2 blocks per graph (f-halves) ----------------
// All 8 H^T GLOAD16s issue up front (after e/stf reg loads, so compiler waits for
// those allow 8 outstanding). Scatter + stats run under stage flight; per-jc
// counted WAITV(6/4/2/0) + barrier gates each 16KB chunk's MFMA (T4).
template<int MODE>
__global__ __launch_bounds__(512) void gat_agg(
    const u16* __restrict__ HT, const int* __restrict__ ei,
    const float* __restrict__ SS, const float* __restrict__ SD,
    const float* __restrict__ bias, const int* __restrict__ valid,
    u16* __restrict__ outU, float* __restrict__ outF)
{
    __shared__ u16 Hts[32768];
    __shared__ u32 cntw[2048];
    __shared__ float stf[512];

    const int tid  = threadIdx.x;
    const int lane = tid & 63;
    const int w    = tid >> 6;
    const int rl   = lane & 15;
    const int grp  = lane >> 4;
    const int q    = blockIdx.x;
    const int g    = (q & 7) * 32 + (q >> 4);
    const int hf   = (q >> 3) & 1;
    const int bb   = g >> 5, tt = g & 31;

    // global reg loads FIRST (their waits then tolerate 8 outstanding GLOADs)
    const int4* es = (const int4*)(ei + (size_t)g * 4096);
    int4 e0 = es[tid], e1 = es[512 + tid];
    float s0 = 0.f, s1 = 0.f;
    if (tid < 128) { s0 = SS[g * 128 + tid]; s1 = SD[g * 128 + tid]; }

    // stage this half's H^T: 8 GLOAD16/thread, issued up front
    const u16* Hg = HT + (size_t)g * 65536 + (size_t)hf * 256 * 128;
    #pragma unroll
    for (int it = 0; it < 8; ++it) {
        int fl = it * 32 + (tid >> 4);
        int blk = tid & 15;
        GLOAD16(Hg + (size_t)fl * 128 + ((blk ^ (fl & 15)) * 8), &Hts[it * 4096 + w * 512]);
    }

    for (int i = tid; i < 2048; i += 512) cntw[i] = 0u;
    if (tid < 128) { stf[tid] = s0; stf[128 + tid] = s1; }
    WAITL0;
    __builtin_amdgcn_s_barrier();

    // ---- edge-count scatter (u4 nibbles), under stage flight ----
    atomicAdd(&cntw[e1.x * 16 + (e0.x >> 3)], 1u << ((e0.x & 7) * 4));
    atomicAdd(&cntw[e1.y * 16 + (e0.y >> 3)], 1u << ((e0.y & 7) * 4));
    atomicAdd(&cntw[e1.z * 16 + (e0.z >> 3)], 1u << ((e0.z & 7) * 4));
    atomicAdd(&cntw[e1.w * 16 + (e0.w >> 3)], 1u << ((e0.w & 7) * 4));
    if (tid < 128) atomicAdd(&cntw[tid * 16 + (tid >> 3)], 1u << ((tid & 7) * 4));
    WAITL0;
    __builtin_amdgcn_s_barrier();

    // ---- softmax stats M, 1/D per dst row (under stage flight) ----
    for (int r = 0; r < 16; ++r) {
        int m = w * 16 + r;
        float sdm = stf[128 + m];
        u32 w0 = cntw[m * 16 + (lane >> 3)];
        u32 w1 = cntw[m * 16 + 8 + (lane >> 3)];
        u32 c0 = (w0 >> ((lane & 7) * 4)) & 15u;
        u32 c1 = (w1 >> ((lane & 7) * 4)) & 15u;
        float E0 = stf[lane] + sdm;      E0 = E0 > 0.f ? E0 : 0.2f * E0;
        float E1 = stf[lane + 64] + sdm; E1 = E1 > 0.f ? E1 : 0.2f * E1;
        float mx = fmaxf(c0 ? E0 : -1e30f, c1 ? E1 : -1e30f);
        #pragma unroll
        for (int off = 1; off < 64; off <<= 1) mx = fmaxf(mx, __shfl_xor(mx, off));
        float p = (c0 ? (float)c0 * __expf(E0 - mx) : 0.f)
                + (c1 ? (float)c1 * __expf(E1 - mx) : 0.f);
        #pragma unroll
        for (int off = 1; off < 64; off <<= 1) p += __shfl_xor(p, off);
        if (lane == 0) { stf[256 + m] = mx; stf[384 + m] = 1.f / p; }
    }
    WAITL0;
    __builtin_amdgcn_s_barrier();

    // ---- alpha fragments (per-lane; cnt/stf are LDS-resident) ----
    const int m = w * 16 + rl;
    const float sdm = stf[128 + m], Mm = stf[256 + m], rDm = stf[384 + m];
    bf16x8 pa[4];
    #pragma unroll
    for (int kb = 0; kb < 4; ++kb) {
        u32 word = cntw[m * 16 + kb * 4 + grp];
        #pragma unroll
        for (int e = 0; e < 8; ++e) {
            u32 c = (word >> (e * 4)) & 15u;
            int s = kb * 32 + grp * 8 + e;
            float ev = stf[s] + sdm; ev = ev > 0.f ? ev : 0.2f * ev;
            float p = c ? (float)c * __expf(ev - Mm) * rDm : 0.f;
            pa[kb][e] = (__bf16)p;
        }
    }

    // ---- AGG: per-jc counted wait + barrier, 16KB chunk each ----
    const float msk = (MODE == 1) ? ((tt < valid[bb]) ? 1.f : 0.f) : 1.f;
    #pragma unroll 1
    for (int jc = 0; jc < 4; ++jc) {
        if      (jc == 0) { WAITV6; }
        else if (jc == 1) { WAITV4; }
        else if (jc == 2) { WAITV2; }
        else              { WAITV0; }
        __builtin_amdgcn_s_barrier();
        f32x4 acc2[4] = {};
        __builtin_amdgcn_s_setprio(1);
        #pragma unroll
        for (int j4 = 0; j4 < 4; ++j4) {
            int fl = jc * 64 + j4 * 16 + rl;
            #pragma unroll
            for (int kb = 0; kb < 4; ++kb) {
                bf16x8 hb = *(const bf16x8*)&Hts[fl * 128 + (((kb * 4 + grp) ^ (fl & 15)) * 8)];
                acc2[j4] = __builtin_amdgcn_mfma_f32_16x16x32_bf16(pa[kb], hb, acc2[j4], 0, 0, 0);
            }
        }
        __builtin_amdgcn_s_setprio(0);
        #pragma unroll
        for (int j4 = 0; j4 < 4; ++j4) {
            int f = hf * 256 + jc * 64 + j4 * 16 + rl;
            float bv = bias[f];
            #pragma unroll
            for (int r = 0; r < 4; ++r) {
                int m2 = w * 16 + grp * 4 + r;
                if (MODE == 0)
                    outU[(size_t)g * 65536 + m2 * 512 + f] = f2bf(gelu_f(acc2[j4][r] + bv));
                else
                    outF[(size_t)g * 65536 + m2 * 512 + f] = (acc2[j4][r] + bv) * msk;
            }
        }
    }
}

// ---------------- time mix: out = gelu(W_time @ y + b_time) + y, in-place ----------------
__global__ __launch_bounds__(256) void timemix_kernel(float* __restrict__ y,
                                                      const float* __restrict__ Wt,
                                                      const float* __restrict__ bt) {
    __shared__ float wsm[1024];
    __shared__ float bts[32];
    int tid = threadIdx.x;
    for (int i = tid; i < 1024; i += 256) wsm[i] = Wt[i];
    if (tid < 32) bts[tid] = bt[tid];
    __syncthreads();
    int blk = blockIdx.x;               // 2048 blocks
    int b = blk >> 8;
    int rem = blk & 255;
    int n = rem >> 1;
    int f = (rem & 1) * 256 + tid;
    size_t base = ((size_t)b * 4096 + n) * 512 + f;
    float ys[32];
    #pragma unroll
    for (int s = 0; s < 32; ++s) ys[s] = y[base + (size_t)s * 65536];
    #pragma unroll
    for (int t = 0; t < 32; ++t) {
        float a = bts[t];
        #pragma unroll
        for (int s = 0; s < 32; ++s) a += wsm[t * 32 + s] * ys[s];
        y[base + (size_t)t * 65536] = gelu_f(a) + ys[t];
    }
}

extern "C" void kernel_launch(void* const* d_in, const int* in_sizes, int n_in,
                              void* d_out, int out_size, void* d_ws, size_t ws_size,
                              hipStream_t stream) {
    const float* x     = (const float*)d_in[0];
    const int*   ei    = (const int*)d_in[1];
    const int*   valid = (const int*)d_in[2];
    const float* W1    = (const float*)d_in[3];
    const float* a1s   = (const float*)d_in[4];
    const float* a1d   = (const float*)d_in[5];
    const float* b1    = (const float*)d_in[6];
    const float* W2    = (const float*)d_in[7];
    const float* a2s   = (const float*)d_in[8];
    const float* a2d   = (const float*)d_in[9];
    const float* b2    = (const float*)d_in[10];
    const float* Wt    = (const float*)d_in[11];
    const float* bt    = (const float*)d_in[12];
    float* out = (float*)d_out;

    char* ws = (char*)d_ws;
    u16* Xb    = (u16*)(ws);                      // 33,554,432 B (x bf16; reused for H1')
    u16* HTb   = (u16*)(ws + 33554432);           // 33,554,432 B (H^T per layer)
    u16* W1b   = (u16*)(ws + 67108864);           //    524,288 B (plain bf16 [f][k])
    u16* W2b   = (u16*)(ws + 67633152);           //    524,288 B
    float* SS1 = (float*)(ws + 68157440);         //    131,072 B (zeroed by prep)
    float* SD1 = (float*)(ws + 68288512);
    float* SS2 = (float*)(ws + 68419584);
    float* SD2 = (float*)(ws + 68550656);

    prep_kernel<<<2048, 256, 0, stream>>>(x, W1, W2, Xb, W1b, W2b, SS1);

    // ---- layer 1 ----
    gat_gemm<<<1024, 256, 0, stream>>>(Xb, W1b, a1s, a1d, HTb, SS1, SD1);
    gat_agg<0><<<512, 512, 0, stream>>>(HTb, ei, SS1, SD1, b1, nullptr, Xb, nullptr);

    // ---- layer 2 ----
    gat_gemm<<<1024, 256, 0, stream>>>(Xb, W2b, a2s, a2d, HTb, SS2, SD2);
    gat_agg<1><<<512, 512, 0, stream>>>(HTb, ei, SS2, SD2, b2, valid, nullptr, out);

    // ---- time mixing (in-place on d_out) ----
    timemix_kernel<<<2048, 256, 0, stream>>>(out, Wt, bt);
}

// Round 19
// 177.402 us; speedup vs baseline: 1.1692x; 1.1692x over previous
//
#include <hip/hip_runtime.h>

using u16 = unsigned short;
using u32 = unsigned int;

typedef __bf16 bf16x8 __attribute__((ext_vector_type(8)));
typedef float  f32x4  __attribute__((ext_vector_type(4)));

__device__ __forceinline__ u16 f2bf(float f) {
    u32 u = __float_as_uint(f);
    u32 r = u + 0x7fffu + ((u >> 16) & 1u);
    return (u16)(r >> 16);
}
__device__ __forceinline__ float gelu_f(float x) {
    return 0.5f * x * (1.0f + erff(x * 0.70710678118654752440f));
}

#define GLOAD16(gp, lp) __builtin_amdgcn_global_load_lds( \
    (const __attribute__((address_space(1))) void*)(gp),  \
    (__attribute__((address_space(3))) void*)(lp), 16, 0, 0)
#define WAITV4  asm volatile("s_waitcnt vmcnt(4)" ::: "memory")
#define WAITV0  asm volatile("s_waitcnt vmcnt(0)" ::: "memory")
#define WAITL0  asm volatile("s_waitcnt lgkmcnt(0)" ::: "memory")

// ---------------- prep: cvt x/W1/W2 -> bf16, zero score buffers ----------------
__global__ __launch_bounds__(256) void prep_kernel(
    const float* __restrict__ x, const float* __restrict__ W1, const float* __restrict__ W2,
    u16* __restrict__ Xb, u16* __restrict__ W1b, u16* __restrict__ W2b,
    float* __restrict__ Z)
{
    const int i0 = blockIdx.x * 256 + threadIdx.x;
    const int stride = gridDim.x * 256;
    if (i0 < 32768) ((float4*)Z)[i0] = make_float4(0.f, 0.f, 0.f, 0.f);
    for (int i = i0; i < 65536; i += stride) {
        float4 v = ((const float4*)W1)[i];
        ushort4 o; o.x = f2bf(v.x); o.y = f2bf(v.y); o.z = f2bf(v.z); o.w = f2bf(v.w);
        ((ushort4*)W1b)[i] = o;
    }
    for (int i = i0; i < 65536; i += stride) {
        float4 v = ((const float4*)W2)[i];
        ushort4 o; o.x = f2bf(v.x); o.y = f2bf(v.y); o.z = f2bf(v.z); o.w = f2bf(v.w);
        ((ushort4*)W2b)[i] = o;
    }
    for (int i = i0; i < 4194304; i += stride) {
        float4 v = ((const float4*)x)[i];
        ushort4 o; o.x = f2bf(v.x); o.y = f2bf(v.y); o.z = f2bf(v.z); o.w = f2bf(v.w);
        ((ushort4*)Xb)[i] = o;
    }
}

// ---------------- kernel A: counted-vmcnt GEMM + LDS-transposed H^T + fused scores ----------------
// Block = (graph g, f-tile tn): 4 waves, 128m x 128f, BK=32 double-buffered.
// k-loop identical to R16 (counted vmcnt, pair-row swizzle, 0 conflicts).
// Epilogue: fragments -> 32KB LDS tile (XOR slot c^fr) -> 8 coalesced 256B row writes.
// XCD remap: bid' = (bid&7)*128 + bid>>3.
__global__ __launch_bounds__(256) void gat_gemm(
    const u16* __restrict__ A, const u16* __restrict__ Wb,
    const float* __restrict__ a_s, const float* __restrict__ a_d,
    u16* __restrict__ HT, float* __restrict__ SS, float* __restrict__ SD)
{
    __shared__ __align__(16) u16 SH[4][128 * 32];   // As=SH[0,1], Bs=SH[2,3]; epilogue: 128x128 H^T tile
    __shared__ float sA[128], dA[128];

    const int tid  = threadIdx.x;
    const int lane = tid & 63;
    const int w    = tid >> 6;       // wave 0..3
    const int wm   = w & 1, wn = w >> 1;
    const int fr   = lane & 15;
    const int grp  = lane >> 4;
    const int bid  = (blockIdx.x & 7) * 128 + (blockIdx.x >> 3);   // XCD-grouped
    const int g    = bid >> 2;
    const int tn   = (bid & 3) * 128;

    if (tid < 128) { sA[tid] = 0.f; dA[tid] = 0.f; }

    const int l3 = lane >> 3, l7 = lane & 7;
    const int cs = l7 ^ l3;
    const u16* Ag0 = A  + (size_t)g * 65536
                   + (size_t)(w * 32 + 2 * l3 + (cs >> 2)) * 512 + (cs & 3) * 8;
    const u16* Bg0 = Wb + (size_t)(tn + w * 32 + 2 * l3 + (cs >> 2)) * 512 + (cs & 3) * 8;

    const int sw = ((((fr & 1) << 2) | grp) ^ ((fr >> 1) & 7)) * 8;

    f32x4 acc[4][4] = {};

    // prologue: stage tiles 0 and 1 (8 loads in flight per wave)
    GLOAD16(Ag0,                 &SH[0][w * 1024]);
    GLOAD16(Ag0 + 16 * 512,      &SH[0][w * 1024 + 512]);
    GLOAD16(Bg0,                 &SH[2][w * 1024]);
    GLOAD16(Bg0 + 16 * 512,      &SH[2][w * 1024 + 512]);
    GLOAD16(Ag0 + 32,            &SH[1][w * 1024]);
    GLOAD16(Ag0 + 16 * 512 + 32, &SH[1][w * 1024 + 512]);
    GLOAD16(Bg0 + 32,            &SH[3][w * 1024]);
    GLOAD16(Bg0 + 16 * 512 + 32, &SH[3][w * 1024 + 512]);

    for (int kt = 0; kt < 16; ++kt) {
        const int cur = kt & 1;
        if (kt < 15) { WAITV4; } else { WAITV0; }
        __builtin_amdgcn_s_barrier();
        bf16x8 af[4], bf[4];
        #pragma unroll
        for (int i = 0; i < 4; ++i) {
            af[i] = *(const bf16x8*)&SH[cur][(wm * 32 + i * 8 + (fr >> 1)) * 64 + sw];
            bf[i] = *(const bf16x8*)&SH[2 + cur][(wn * 32 + i * 8 + (fr >> 1)) * 64 + sw];
        }
        WAITL0;
        __builtin_amdgcn_sched_barrier(0);
        __builtin_amdgcn_s_barrier();
        if (kt < 14) {
            GLOAD16(Ag0 + (kt + 2) * 32,            &SH[cur][w * 1024]);
            GLOAD16(Ag0 + 16 * 512 + (kt + 2) * 32, &SH[cur][w * 1024 + 512]);
            GLOAD16(Bg0 + (kt + 2) * 32,            &SH[2 + cur][w * 1024]);
            GLOAD16(Bg0 + 16 * 512 + (kt + 2) * 32, &SH[2 + cur][w * 1024 + 512]);
        }
        #pragma unroll
        for (int i = 0; i < 4; ++i)
            #pragma unroll
            for (int j = 0; j < 4; ++j)
                acc[i][j] = __builtin_amdgcn_mfma_f32_16x16x32_bf16(af[i], bf[j], acc[i][j], 0, 0, 0);
    }
    // post-loop: the final in-loop barrier followed all LDS reads; staging GLOADs are
    // drained (WAITV0 at kt=15). Each wave now writes a disjoint (fl,node) quadrant.

    u16* Hs = &SH[0][0];   // 128f x 128node tile, slot-swizzled: [fl][ (c ^ (fl&15))*8 + in8 ]

    // ---- fragments -> LDS H^T tile ----
    #pragma unroll
    for (int i = 0; i < 4; ++i) {
        int node0 = wm * 64 + i * 16 + grp * 4;
        int c = node0 >> 3, in8 = node0 & 7;
        #pragma unroll
        for (int j = 0; j < 4; ++j) {
            int fl = wn * 64 + j * 16 + fr;
            ushort4 o;
            o.x = f2bf(acc[i][j][0]); o.y = f2bf(acc[i][j][1]);
            o.z = f2bf(acc[i][j][2]); o.w = f2bf(acc[i][j][3]);
            *(ushort4*)&Hs[fl * 128 + ((c ^ fr) * 8) + in8] = o;
        }
    }

    // ---- fused scores (from acc, unchanged) ----
    float asv[4], adv[4];
    #pragma unroll
    for (int j = 0; j < 4; ++j) {
        int f = tn + wn * 64 + j * 16 + fr;
        asv[j] = a_s[f]; adv[j] = a_d[f];
    }
    #pragma unroll
    for (int i = 0; i < 4; ++i) {
        int node0 = wm * 64 + i * 16 + grp * 4;
        #pragma unroll
        for (int r = 0; r < 4; ++r) {
            float s = acc[i][0][r] * asv[0] + acc[i][1][r] * asv[1]
                    + acc[i][2][r] * asv[2] + acc[i][3][r] * asv[3];
            float d = acc[i][0][r] * adv[0] + acc[i][1][r] * adv[1]
                    + acc[i][2][r] * adv[2] + acc[i][3][r] * adv[3];
            #pragma unroll
            for (int off = 1; off < 16; off <<= 1) {
                s += __shfl_xor(s, off);
                d += __shfl_xor(d, off);
            }
            if (fr == 0) {
                atomicAdd(&sA[node0 + r], s);
                atomicAdd(&dA[node0 + r], d);
            }
        }
    }
    __syncthreads();

    // ---- coalesced H^T write-out: 16 lanes cover one contiguous 256B f-row ----
    u16* Hg = HT + (size_t)g * 65536;
    #pragma unroll
    for (int it = 0; it < 8; ++it) {
        int fl  = it * 16 + (tid >> 4);
        int blk = tid & 15;
        uint4 v = *(const uint4*)&Hs[fl * 128 + ((blk ^ (fl & 15)) * 8)];
        *(uint4*)&Hg[(size_t)(tn + fl) * 128 + blk * 8] = v;
    }
    if (tid < 128) {
        atomicAdd(&SS[g * 128 + tid], sA[tid]);
        atomicAdd(&SD[g * 128 + tid], dA[tid]);
    }
}

// ---------------- kernel B: alpha + AGG, 2 blocks per graph (f-halves), LDS-staged ----------------
template<int MODE>
__global__ __launch_bounds__(512) void gat_agg(
    const u16* __restrict__ HT, const int* __restrict__ ei,
    const float* __restrict__ SS, const float* __restrict__ SD,
    const float* __restrict__ bias, const int* __restrict__ valid,
    u16* __restrict__ outU, float* __restrict__ outF)
{
    __shared__ u16 Hts[32768];
    __shared__ u32 cntw[2048];
    __shared__ float stf[512];

    const int tid  = threadIdx.x;
    const int lane = tid & 63;
    const int w    = tid >> 6;
    const int rl   = lane & 15;
    const int grp  = lane >> 4;
    const int q    = blockIdx.x;
    const int g    = (q & 7) * 32 + (q >> 4);
    const int hf   = (q >> 3) & 1;
    const int bb   = g >> 5, tt = g & 31;

    const int4* es = (const int4*)(ei + (size_t)g * 4096);
    int4 e0 = es[tid], e1 = es[512 + tid];

    // stage this half's H^T: lds[fl][blk] <- global[f][blk ^ (f&15)] (f = hf*256 + fl)
    const u16* Hg = HT + (size_t)g * 65536 + (size_t)hf * 256 * 128;
    #pragma unroll
    for (int it = 0; it < 8; ++it) {
        int fl = it * 32 + (tid >> 4);
        int blk = tid & 15;
        GLOAD16(Hg + (size_t)fl * 128 + ((blk ^ (fl & 15)) * 8), &Hts[it * 4096 + w * 512]);
    }

    for (int i = tid; i < 2048; i += 512) cntw[i] = 0u;
    if (tid < 128) {
        stf[tid]       = SS[g * 128 + tid];
        stf[128 + tid] = SD[g * 128 + tid];
    }
    __syncthreads();   // drains GLOADs + zero/score writes

    // ---- edge-count scatter (u4 nibbles) ----
    atomicAdd(&cntw[e1.x * 16 + (e0.x >> 3)], 1u << ((e0.x & 7) * 4));
    atomicAdd(&cntw[e1.y * 16 + (e0.y >> 3)], 1u << ((e0.y & 7) * 4));
    atomicAdd(&cntw[e1.z * 16 + (e0.z >> 3)], 1u << ((e0.z & 7) * 4));
    atomicAdd(&cntw[e1.w * 16 + (e0.w >> 3)], 1u << ((e0.w & 7) * 4));
    if (tid < 128) atomicAdd(&cntw[tid * 16 + (tid >> 3)], 1u << ((tid & 7) * 4));
    __syncthreads();

    // ---- softmax stats M, 1/D per dst row ----
    for (int r = 0; r < 16; ++r) {
        int m = w * 16 + r;
        float sdm = stf[128 + m];
        u32 w0 = cntw[m * 16 + (lane >> 3)];
        u32 w1 = cntw[m * 16 + 8 + (lane >> 3)];
        u32 c0 = (w0 >> ((lane & 7) * 4)) & 15u;
        u32 c1 = (w1 >> ((lane & 7) * 4)) & 15u;
        float E0 = stf[lane] + sdm;      E0 = E0 > 0.f ? E0 : 0.2f * E0;
        float E1 = stf[lane + 64] + sdm; E1 = E1 > 0.f ? E1 : 0.2f * E1;
        float mx = fmaxf(c0 ? E0 : -1e30f, c1 ? E1 : -1e30f);
        #pragma unroll
        for (int off = 1; off < 64; off <<= 1) mx = fmaxf(mx, __shfl_xor(mx, off));
        float p = (c0 ? (float)c0 * __expf(E0 - mx) : 0.f)
                + (c1 ? (float)c1 * __expf(E1 - mx) : 0.f);
        #pragma unroll
        for (int off = 1; off < 64; off <<= 1) p += __shfl_xor(p, off);
        if (lane == 0) { stf[256 + m] = mx; stf[384 + m] = 1.f / p; }
    }
    __syncthreads();

    // ---- alpha fragments (per-lane) ----
    const int m = w * 16 + rl;
    const float sdm = stf[128 + m], Mm = stf[256 + m], rDm = stf[384 + m];
    bf16x8 pa[4];
    #pragma unroll
    for (int kb = 0; kb < 4; ++kb) {
        u32 word = cntw[m * 16 + kb * 4 + grp];
        #pragma unroll
        for (int e = 0; e < 8; ++e) {
            u32 c = (word >> (e * 4)) & 15u;
            int s = kb * 32 + grp * 8 + e;
            float ev = stf[s] + sdm; ev = ev > 0.f ? ev : 0.2f * ev;
            float p = c ? (float)c * __expf(ev - Mm) * rDm : 0.f;
            pa[kb][e] = (__bf16)p;
        }
    }

    // ---- AGG over this half's 256 f (4 chunks of 64), H^T from LDS ----
    const float msk = (MODE == 1) ? ((tt < valid[bb]) ? 1.f : 0.f) : 1.f;
    #pragma unroll 1
    for (int jc = 0; jc < 4; ++jc) {
        f32x4 acc2[4] = {};
        __builtin_amdgcn_s_setprio(1);
        #pragma unroll
        for (int j4 = 0; j4 < 4; ++j4) {
            int fl = jc * 64 + j4 * 16 + rl;
            #pragma unroll
            for (int kb = 0; kb < 4; ++kb) {
                bf16x8 hb = *(const bf16x8*)&Hts[fl * 128 + (((kb * 4 + grp) ^ (fl & 15)) * 8)];
                acc2[j4] = __builtin_amdgcn_mfma_f32_16x16x32_bf16(pa[kb], hb, acc2[j4], 0, 0, 0);
            }
        }
        __builtin_amdgcn_s_setprio(0);
        #pragma unroll
        for (int j4 = 0; j4 < 4; ++j4) {
            int f = hf * 256 + jc * 64 + j4 * 16 + rl;
            float bv = bias[f];
            #pragma unroll
            for (int r = 0; r < 4; ++r) {
                int m2 = w * 16 + grp * 4 + r;
                if (MODE == 0)
                    outU[(size_t)g * 65536 + m2 * 512 + f] = f2bf(gelu_f(acc2[j4][r] + bv));
                else
                    outF[(size_t)g * 65536 + m2 * 512 + f] = (acc2[j4][r] + bv) * msk;
            }
        }
    }
}

// ---------------- time mix: out = gelu(W_time @ y + b_time) + y, in-place ----------------
__global__ __launch_bounds__(256) void timemix_kernel(float* __restrict__ y,
                                                      const float* __restrict__ Wt,
                                                      const float* __restrict__ bt) {
    __shared__ float wsm[1024];
    __shared__ float bts[32];
    int tid = threadIdx.x;
    for (int i = tid; i < 1024; i += 256) wsm[i] = Wt[i];
    if (tid < 32) bts[tid] = bt[tid];
    __syncthreads();
    int blk = blockIdx.x;               // 2048 blocks
    int b = blk >> 8;
    int rem = blk & 255;
    int n = rem >> 1;
    int f = (rem & 1) * 256 + tid;
    size_t base = ((size_t)b * 4096 + n) * 512 + f;
    float ys[32];
    #pragma unroll
    for (int s = 0; s < 32; ++s) ys[s] = y[base + (size_t)s * 65536];
    #pragma unroll
    for (int t = 0; t < 32; ++t) {
        float a = bts[t];
        #pragma unroll
        for (int s = 0; s < 32; ++s) a += wsm[t * 32 + s] * ys[s];
        y[base + (size_t)t * 65536] = gelu_f(a) + ys[t];
    }
}

extern "C" void kernel_launch(void* const* d_in, const int* in_sizes, int n_in,
                              void* d_out, int out_size, void* d_ws, size_t ws_size,
                              hipStream_t stream) {
    const float* x     = (const float*)d_in[0];
    const int*   ei    = (const int*)d_in[1];
    const int*   valid = (const int*)d_in[2];
    const float* W1    = (const float*)d_in[3];
    const float* a1s   = (const float*)d_in[4];
    const float* a1d   = (const float*)d_in[5];
    const float* b1    = (const float*)d_in[6];
    const float* W2    = (const float*)d_in[7];
    const float* a2s   = (const float*)d_in[8];
    const float* a2d   = (const float*)d_in[9];
    const float* b2    = (const float*)d_in[10];
    const float* Wt    = (const float*)d_in[11];
    const float* bt    = (const float*)d_in[12];
    float* out = (float*)d_out;

    char* ws = (char*)d_ws;
    u16* Xb    = (u16*)(ws);                      // 33,554,432 B (x bf16; reused for H1')
    u16* HTb   = (u16*)(ws + 33554432);           // 33,554,432 B (H^T per layer)
    u16* W1b   = (u16*)(ws + 67108864);           //    524,288 B
    u16* W2b   = (u16*)(ws + 67633152);           //    524,288 B
    float* SS1 = (float*)(ws + 68157440);         //    131,072 B (zeroed by prep)
    float* SD1 = (float*)(ws + 68288512);
    float* SS2 = (float*)(ws + 68419584);
    float* SD2 = (float*)(ws + 68550656);

    prep_kernel<<<2048, 256, 0, stream>>>(x, W1, W2, Xb, W1b, W2b, SS1);

    // ---- layer 1 ----
    gat_gemm<<<1024, 256, 0, stream>>>(Xb, W1b, a1s, a1d, HTb, SS1, SD1);
    gat_agg<0><<<512, 512, 0, stream>>>(HTb, ei, SS1, SD1, b1, nullptr, Xb, nullptr);

    // ---- layer 2 ----
    gat_gemm<<<1024, 256, 0, stream>>>(Xb, W2b, a2s, a2d, HTb, SS2, SD2);
    gat_agg<1><<<512, 512, 0, stream>>>(HTb, ei, SS2, SD2, b2, valid, nullptr, out);

    // ---- time mixing (in-place on d_out) ----
    timemix_kernel<<<2048, 256, 0, stream>>>(out, Wt, bt);
}

// Round 20
// 176.184 us; speedup vs baseline: 1.1773x; 1.0069x over previous
//
#include <hip/hip_runtime.h>

using u16 = unsigned short;
using u32 = unsigned int;

typedef __bf16 bf16x8 __attribute__((ext_vector_type(8)));
typedef float  f32x4  __attribute__((ext_vector_type(4)));

__device__ __forceinline__ u16 f2bf(float f) {
    u32 u = __float_as_uint(f);
    u32 r = u + 0x7fffu + ((u >> 16) & 1u);
    return (u16)(r >> 16);
}
__device__ __forceinline__ float bf2f(u16 u) {
    return __uint_as_float(((u32)u) << 16);
}
__device__ __forceinline__ float gelu_f(float x) {
    return 0.5f * x * (1.0f + erff(x * 0.70710678118654752440f));
}

#define GLOAD16(gp, lp) __builtin_amdgcn_global_load_lds( \
    (const __attribute__((address_space(1))) void*)(gp),  \
    (__attribute__((address_space(3))) void*)(lp), 16, 0, 0)
#define WAITV4  asm volatile("s_waitcnt vmcnt(4)" ::: "memory")
#define WAITV0  asm volatile("s_waitcnt vmcnt(0)" ::: "memory")
#define WAITL0  asm volatile("s_waitcnt lgkmcnt(0)" ::: "memory")

// ---------------- prep: cvt x/W1/W2 -> bf16, zero score buffers ----------------
__global__ __launch_bounds__(256) void prep_kernel(
    const float* __restrict__ x, const float* __restrict__ W1, const float* __restrict__ W2,
    u16* __restrict__ Xb, u16* __restrict__ W1b, u16* __restrict__ W2b,
    float* __restrict__ Z)
{
    const int i0 = blockIdx.x * 256 + threadIdx.x;
    const int stride = gridDim.x * 256;
    if (i0 < 32768) ((float4*)Z)[i0] = make_float4(0.f, 0.f, 0.f, 0.f);
    for (int i = i0; i < 65536; i += stride) {
        float4 v = ((const float4*)W1)[i];
        ushort4 o; o.x = f2bf(v.x); o.y = f2bf(v.y); o.z = f2bf(v.z); o.w = f2bf(v.w);
        ((ushort4*)W1b)[i] = o;
    }
    for (int i = i0; i < 65536; i += stride) {
        float4 v = ((const float4*)W2)[i];
        ushort4 o; o.x = f2bf(v.x); o.y = f2bf(v.y); o.z = f2bf(v.z); o.w = f2bf(v.w);
        ((ushort4*)W2b)[i] = o;
    }
    for (int i = i0; i < 4194304; i += stride) {
        float4 v = ((const float4*)x)[i];
        ushort4 o; o.x = f2bf(v.x); o.y = f2bf(v.y); o.z = f2bf(v.z); o.w = f2bf(v.w);
        ((ushort4*)Xb)[i] = o;
    }
}

// ---------------- kernel A: counted-vmcnt GEMM + LDS-transposed H^T + fused scores ----------------
// (R19-verified.) Block = (graph g, f-tile tn): 4 waves, 128m x 128f, BK=32 dbuf.
__global__ __launch_bounds__(256) void gat_gemm(
    const u16* __restrict__ A, const u16* __restrict__ Wb,
    const float* __restrict__ a_s, const float* __restrict__ a_d,
    u16* __restrict__ HT, float* __restrict__ SS, float* __restrict__ SD)
{
    __shared__ __align__(16) u16 SH[4][128 * 32];   // As=SH[0,1], Bs=SH[2,3]; epilogue: H^T tile
    __shared__ float sA[128], dA[128];

    const int tid  = threadIdx.x;
    const int lane = tid & 63;
    const int w    = tid >> 6;       // wave 0..3
    const int wm   = w & 1, wn = w >> 1;
    const int fr   = lane & 15;
    const int grp  = lane >> 4;
    const int bid  = (blockIdx.x & 7) * 128 + (blockIdx.x >> 3);   // XCD-grouped
    const int g    = bid >> 2;
    const int tn   = (bid & 3) * 128;

    if (tid < 128) { sA[tid] = 0.f; dA[tid] = 0.f; }

    const int l3 = lane >> 3, l7 = lane & 7;
    const int cs = l7 ^ l3;
    const u16* Ag0 = A  + (size_t)g * 65536
                   + (size_t)(w * 32 + 2 * l3 + (cs >> 2)) * 512 + (cs & 3) * 8;
    const u16* Bg0 = Wb + (size_t)(tn + w * 32 + 2 * l3 + (cs >> 2)) * 512 + (cs & 3) * 8;

    const int sw = ((((fr & 1) << 2) | grp) ^ ((fr >> 1) & 7)) * 8;

    f32x4 acc[4][4] = {};

    // prologue: stage tiles 0 and 1 (8 loads in flight per wave)
    GLOAD16(Ag0,                 &SH[0][w * 1024]);
    GLOAD16(Ag0 + 16 * 512,      &SH[0][w * 1024 + 512]);
    GLOAD16(Bg0,                 &SH[2][w * 1024]);
    GLOAD16(Bg0 + 16 * 512,      &SH[2][w * 1024 + 512]);
    GLOAD16(Ag0 + 32,            &SH[1][w * 1024]);
    GLOAD16(Ag0 + 16 * 512 + 32, &SH[1][w * 1024 + 512]);
    GLOAD16(Bg0 + 32,            &SH[3][w * 1024]);
    GLOAD16(Bg0 + 16 * 512 + 32, &SH[3][w * 1024 + 512]);

    for (int kt = 0; kt < 16; ++kt) {
        const int cur = kt & 1;
        if (kt < 15) { WAITV4; } else { WAITV0; }
        __builtin_amdgcn_s_barrier();
        bf16x8 af[4], bf[4];
        #pragma unroll
        for (int i = 0; i < 4; ++i) {
            af[i] = *(const bf16x8*)&SH[cur][(wm * 32 + i * 8 + (fr >> 1)) * 64 + sw];
            bf[i] = *(const bf16x8*)&SH[2 + cur][(wn * 32 + i * 8 + (fr >> 1)) * 64 + sw];
        }
        WAITL0;
        __builtin_amdgcn_sched_barrier(0);
        __builtin_amdgcn_s_barrier();
        if (kt < 14) {
            GLOAD16(Ag0 + (kt + 2) * 32,            &SH[cur][w * 1024]);
            GLOAD16(Ag0 + 16 * 512 + (kt + 2) * 32, &SH[cur][w * 1024 + 512]);
            GLOAD16(Bg0 + (kt + 2) * 32,            &SH[2 + cur][w * 1024]);
            GLOAD16(Bg0 + 16 * 512 + (kt + 2) * 32, &SH[2 + cur][w * 1024 + 512]);
        }
        #pragma unroll
        for (int i = 0; i < 4; ++i)
            #pragma unroll
            for (int j = 0; j < 4; ++j)
                acc[i][j] = __builtin_amdgcn_mfma_f32_16x16x32_bf16(af[i], bf[j], acc[i][j], 0, 0, 0);
    }

    u16* Hs = &SH[0][0];   // 128f x 128node tile, slot-swizzled

    // ---- fragments -> LDS H^T tile ----
    #pragma unroll
    for (int i = 0; i < 4; ++i) {
        int node0 = wm * 64 + i * 16 + grp * 4;
        int c = node0 >> 3, in8 = node0 & 7;
        #pragma unroll
        for (int j = 0; j < 4; ++j) {
            int fl = wn * 64 + j * 16 + fr;
            ushort4 o;
            o.x = f2bf(acc[i][j][0]); o.y = f2bf(acc[i][j][1]);
            o.z = f2bf(acc[i][j][2]); o.w = f2bf(acc[i][j][3]);
            *(ushort4*)&Hs[fl * 128 + ((c ^ fr) * 8) + in8] = o;
        }
    }

    // ---- fused scores ----
    float asv[4], adv[4];
    #pragma unroll
    for (int j = 0; j < 4; ++j) {
        int f = tn + wn * 64 + j * 16 + fr;
        asv[j] = a_s[f]; adv[j] = a_d[f];
    }
    #pragma unroll
    for (int i = 0; i < 4; ++i) {
        int node0 = wm * 64 + i * 16 + grp * 4;
        #pragma unroll
        for (int r = 0; r < 4; ++r) {
            float s = acc[i][0][r] * asv[0] + acc[i][1][r] * asv[1]
                    + acc[i][2][r] * asv[2] + acc[i][3][r] * asv[3];
            float d = acc[i][0][r] * adv[0] + acc[i][1][r] * adv[1]
                    + acc[i][2][r] * adv[2] + acc[i][3][r] * adv[3];
            #pragma unroll
            for (int off = 1; off < 16; off <<= 1) {
                s += __shfl_xor(s, off);
                d += __shfl_xor(d, off);
            }
            if (fr == 0) {
                atomicAdd(&sA[node0 + r], s);
                atomicAdd(&dA[node0 + r], d);
            }
        }
    }
    __syncthreads();

    // ---- coalesced H^T write-out ----
    u16* Hg = HT + (size_t)g * 65536;
    #pragma unroll
    for (int it = 0; it < 8; ++it) {
        int fl  = it * 16 + (tid >> 4);
        int blk = tid & 15;
        uint4 v = *(const uint4*)&Hs[fl * 128 + ((blk ^ (fl & 15)) * 8)];
        *(uint4*)&Hg[(size_t)(tn + fl) * 128 + blk * 8] = v;
    }
    if (tid < 128) {
        atomicAdd(&SS[g * 128 + tid], sA[tid]);
        atomicAdd(&SD[g * 128 + tid], dA[tid]);
    }
}

// ---------------- kernel B: alpha + AGG, 2 blocks per graph (f-halves), LDS-staged ----------------
// MODE 0: outU = bf16 gelu(AGG + bias)  (H1' for layer 2)
// MODE 1: outU = bf16 (AGG + bias)*mask (y handoff to timemix)
template<int MODE>
__global__ __launch_bounds__(512) void gat_agg(
    const u16* __restrict__ HT, const int* __restrict__ ei,
    const float* __restrict__ SS, const float* __restrict__ SD,
    const float* __restrict__ bias, const int* __restrict__ valid,
    u16* __restrict__ outU)
{
    __shared__ u16 Hts[32768];
    __shared__ u32 cntw[2048];
    __shared__ float stf[512];

    const int tid  = threadIdx.x;
    const int lane = tid & 63;
    const int w    = tid >> 6;
    const int rl   = lane & 15;
    const int grp  = lane >> 4;
    const int q    = blockIdx.x;
    const int g    = (q & 7) * 32 + (q >> 4);
    const int hf   = (q >> 3) & 1;
    const int bb   = g >> 5, tt = g & 31;

    const int4* es = (const int4*)(ei + (size_t)g * 4096);
    int4 e0 = es[tid], e1 = es[512 + tid];

    // stage this half's H^T: lds[fl][blk] <- global[f][blk ^ (f&15)]
    const u16* Hg = HT + (size_t)g * 65536 + (size_t)hf * 256 * 128;
    #pragma unroll
    for (int it = 0; it < 8; ++it) {
        int fl = it * 32 + (tid >> 4);
        int blk = tid & 15;
        GLOAD16(Hg + (size_t)fl * 128 + ((blk ^ (fl & 15)) * 8), &Hts[it * 4096 + w * 512]);
    }

    for (int i = tid; i < 2048; i += 512) cntw[i] = 0u;
    if (tid < 128) {
        stf[tid]       = SS[g * 128 + tid];
        stf[128 + tid] = SD[g * 128 + tid];
    }
    __syncthreads();

    // ---- edge-count scatter (u4 nibbles) ----
    atomicAdd(&cntw[e1.x * 16 + (e0.x >> 3)], 1u << ((e0.x & 7) * 4));
    atomicAdd(&cntw[e1.y * 16 + (e0.y >> 3)], 1u << ((e0.y & 7) * 4));
    atomicAdd(&cntw[e1.z * 16 + (e0.z >> 3)], 1u << ((e0.z & 7) * 4));
    atomicAdd(&cntw[e1.w * 16 + (e0.w >> 3)], 1u << ((e0.w & 7) * 4));
    if (tid < 128) atomicAdd(&cntw[tid * 16 + (tid >> 3)], 1u << ((tid & 7) * 4));
    __syncthreads();

    // ---- softmax stats M, 1/D per dst row ----
    for (int r = 0; r < 16; ++r) {
        int m = w * 16 + r;
        float sdm = stf[128 + m];
        u32 w0 = cntw[m * 16 + (lane >> 3)];
        u32 w1 = cntw[m * 16 + 8 + (lane >> 3)];
        u32 c0 = (w0 >> ((lane & 7) * 4)) & 15u;
        u32 c1 = (w1 >> ((lane & 7) * 4)) & 15u;
        float E0 = stf[lane] + sdm;      E0 = E0 > 0.f ? E0 : 0.2f * E0;
        float E1 = stf[lane + 64] + sdm; E1 = E1 > 0.f ? E1 : 0.2f * E1;
        float mx = fmaxf(c0 ? E0 : -1e30f, c1 ? E1 : -1e30f);
        #pragma unroll
        for (int off = 1; off < 64; off <<= 1) mx = fmaxf(mx, __shfl_xor(mx, off));
        float p = (c0 ? (float)c0 * __expf(E0 - mx) : 0.f)
                + (c1 ? (float)c1 * __expf(E1 - mx) : 0.f);
        #pragma unroll
        for (int off = 1; off < 64; off <<= 1) p += __shfl_xor(p, off);
        if (lane == 0) { stf[256 + m] = mx; stf[384 + m] = 1.f / p; }
    }
    __syncthreads();

    // ---- alpha fragments (per-lane) ----
    const int m = w * 16 + rl;
    const float sdm = stf[128 + m], Mm = stf[256 + m], rDm = stf[384 + m];
    bf16x8 pa[4];
    #pragma unroll
    for (int kb = 0; kb < 4; ++kb) {
        u32 word = cntw[m * 16 + kb * 4 + grp];
        #pragma unroll
        for (int e = 0; e < 8; ++e) {
            u32 c = (word >> (e * 4)) & 15u;
            int s = kb * 32 + grp * 8 + e;
            float ev = stf[s] + sdm; ev = ev > 0.f ? ev : 0.2f * ev;
            float p = c ? (float)c * __expf(ev - Mm) * rDm : 0.f;
            pa[kb][e] = (__bf16)p;
        }
    }

    // ---- AGG over this half's 256 f (4 chunks of 64), H^T from LDS ----
    const float msk = (MODE == 1) ? ((tt < valid[bb]) ? 1.f : 0.f) : 1.f;
    #pragma unroll 1
    for (int jc = 0; jc < 4; ++jc) {
        f32x4 acc2[4] = {};
        __builtin_amdgcn_s_setprio(1);
        #pragma unroll
        for (int j4 = 0; j4 < 4; ++j4) {
            int fl = jc * 64 + j4 * 16 + rl;
            #pragma unroll
            for (int kb = 0; kb < 4; ++kb) {
                bf16x8 hb = *(const bf16x8*)&Hts[fl * 128 + (((kb * 4 + grp) ^ (fl & 15)) * 8)];
                acc2[j4] = __builtin_amdgcn_mfma_f32_16x16x32_bf16(pa[kb], hb, acc2[j4], 0, 0, 0);
            }
        }
        __builtin_amdgcn_s_setprio(0);
        #pragma unroll
        for (int j4 = 0; j4 < 4; ++j4) {
            int f = hf * 256 + jc * 64 + j4 * 16 + rl;
            float bv = bias[f];
            #pragma unroll
            for (int r = 0; r < 4; ++r) {
                int m2 = w * 16 + grp * 4 + r;
                if (MODE == 0)
                    outU[(size_t)g * 65536 + m2 * 512 + f] = f2bf(gelu_f(acc2[j4][r] + bv));
                else
                    outU[(size_t)g * 65536 + m2 * 512 + f] = f2bf((acc2[j4][r] + bv) * msk);
            }
        }
    }
}

// ---------------- time mix: out = gelu(W_time @ y + b_time) + y (y bf16 -> out f32) ----------------
__global__ __launch_bounds__(256) void timemix_kernel(const u16* __restrict__ yb,
                                                      float* __restrict__ out,
                                                      const float* __restrict__ Wt,
                                                      const float* __restrict__ bt) {
    __shared__ float wsm[1024];
    __shared__ float bts[32];
    int tid = threadIdx.x;
    for (int i = tid; i < 1024; i += 256) wsm[i] = Wt[i];
    if (tid < 32) bts[tid] = bt[tid];
    __syncthreads();
    int blk = blockIdx.x;               // 2048 blocks
    int b = blk >> 8;
    int rem = blk & 255;
    int n = rem >> 1;
    int f = (rem & 1) * 256 + tid;
    size_t base = ((size_t)b * 4096 + n) * 512 + f;   // (b,0,n,f); s-stride = 65536
    float ys[32];
    #pragma unroll
    for (int s = 0; s < 32; ++s) ys[s] = bf2f(yb[base + (size_t)s * 65536]);
    #pragma unroll
    for (int t = 0; t < 32; ++t) {
        float a = bts[t];
        #pragma unroll
        for (int s = 0; s < 32; ++s) a += wsm[t * 32 + s] * ys[s];
        out[base + (size_t)t * 65536] = gelu_f(a) + ys[t];
    }
}

extern "C" void kernel_launch(void* const* d_in, const int* in_sizes, int n_in,
                              void* d_out, int out_size, void* d_ws, size_t ws_size,
                              hipStream_t stream) {
    const float* x     = (const float*)d_in[0];
    const int*   ei    = (const int*)d_in[1];
    const int*   valid = (const int*)d_in[2];
    const float* W1    = (const float*)d_in[3];
    const float* a1s   = (const float*)d_in[4];
    const float* a1d   = (const float*)d_in[5];
    const float* b1    = (const float*)d_in[6];
    const float* W2    = (const float*)d_in[7];
    const float* a2s   = (const float*)d_in[8];
    const float* a2d   = (const float*)d_in[9];
    const float* b2    = (const float*)d_in[10];
    const float* Wt    = (const float*)d_in[11];
    const float* bt    = (const float*)d_in[12];
    float* out = (float*)d_out;

    char* ws = (char*)d_ws;
    u16* Xb    = (u16*)(ws);                      // 33,554,432 B (x bf16 -> H1' -> y bf16)
    u16* HTb   = (u16*)(ws + 33554432);           // 33,554,432 B (H^T per layer)
    u16* W1b   = (u16*)(ws + 67108864);           //    524,288 B
    u16* W2b   = (u16*)(ws + 67633152);           //    524,288 B
    float* SS1 = (float*)(ws + 68157440);         //    131,072 B (zeroed by prep)
    float* SD1 = (float*)(ws + 68288512);
    float* SS2 = (float*)(ws + 68419584);
    float* SD2 = (float*)(ws + 68550656);

    prep_kernel<<<2048, 256, 0, stream>>>(x, W1, W2, Xb, W1b, W2b, SS1);

    // ---- layer 1 ----
    gat_gemm<<<1024, 256, 0, stream>>>(Xb, W1b, a1s, a1d, HTb, SS1, SD1);
    gat_agg<0><<<512, 512, 0, stream>>>(HTb, ei, SS1, SD1, b1, nullptr, Xb);

    // ---- layer 2 ----
    gat_gemm<<<1024, 256, 0, stream>>>(Xb, W2b, a2s, a2d, HTb, SS2, SD2);
    gat_agg<1><<<512, 512, 0, stream>>>(HTb, ei, SS2, SD2, b2, valid, Xb);

    // ---- time mixing: y (bf16, in Xb) -> out (f32) ----
    timemix_kernel<<<2048, 256, 0, stream>>>(Xb, out, Wt, bt);
}